// Round 1
// baseline (458.489 us; speedup 1.0000x reference)
//
#include <hip/hip_runtime.h>

#define BB 16
#define SS 2048
#define DD 128
#define SCALE 0.08838834764831845f  // 1/sqrt(128)

typedef __attribute__((ext_vector_type(8))) short bf16x8;
typedef __attribute__((ext_vector_type(4))) float f32x4;

__device__ __forceinline__ unsigned short f2bf(float f) {
    union { float f; unsigned int u; } v; v.f = f;
    unsigned int u = v.u;
    return (unsigned short)((u + 0x7fffu + ((u >> 16) & 1u)) >> 16);  // RNE
}

// ---- pre-pass 1: fp32 -> bf16 contiguous copy (used for Q and K) ----
__global__ __launch_bounds__(256) void cvt_bf16_kernel(const float* __restrict__ src,
                                                       unsigned short* __restrict__ dst) {
    int idx = (blockIdx.x * 256 + threadIdx.x) * 4;
    float4 f = *(const float4*)(src + idx);
    ushort4 o;
    o.x = f2bf(f.x); o.y = f2bf(f.y); o.z = f2bf(f.z); o.w = f2bf(f.w);
    *(ushort4*)(dst + idx) = o;
}

// ---- pre-pass 2: V [B][S][D] fp32 -> Vt [B][D][S] bf16 (transpose) ----
__global__ __launch_bounds__(256) void transpose_v_kernel(const float* __restrict__ v,
                                                          unsigned short* __restrict__ vt) {
    __shared__ unsigned short sT[64 * 132];
    int b = blockIdx.x >> 5;
    int s0 = (blockIdx.x & 31) * 64;
    int tid = threadIdx.x;
#pragma unroll
    for (int rnd = 0; rnd < 8; ++rnd) {
        int slot = rnd * 256 + tid;
        int row = slot >> 5;        // 0..63 (s)
        int c4 = (slot & 31) * 4;   // 0..124 (d)
        float4 f = *(const float4*)(v + (size_t)(b * SS + s0 + row) * DD + c4);
        unsigned short* p = &sT[row * 132 + c4];
        p[0] = f2bf(f.x); p[1] = f2bf(f.y); p[2] = f2bf(f.z); p[3] = f2bf(f.w);
    }
    __syncthreads();
#pragma unroll
    for (int rnd = 0; rnd < 4; ++rnd) {
        int slot = rnd * 256 + tid;
        int d = slot >> 3;          // 0..127
        int k8 = (slot & 7) * 8;    // 0..56
        __align__(16) unsigned short tmp[8];
#pragma unroll
        for (int e = 0; e < 8; ++e) tmp[e] = sT[(k8 + e) * 132 + d];
        *(ushort4*)(vt + (size_t)(b * DD + d) * SS + s0 + k8) = *(ushort4*)&tmp[0];
        *(ushort4*)(vt + (size_t)(b * DD + d) * SS + s0 + k8 + 4) = *(ushort4*)&tmp[4];
    }
}

// ---- main fused attention: one block per (b, 64-row q tile) ----
__global__ __launch_bounds__(256) void attn_kernel(const unsigned short* __restrict__ Qb,
                                                   const unsigned short* __restrict__ Kb,
                                                   const unsigned short* __restrict__ Vt,
                                                   const int* __restrict__ mask,
                                                   float* __restrict__ outO,
                                                   float* __restrict__ outA) {
    // LDS tiles, padded for <=2-way bank aliasing on b128 frag reads
    __shared__ unsigned short sQ[64 * 136];   // [qrow][d]   stride 272B (16B-aligned)
    __shared__ unsigned short sK[64 * 136];   // [krow][d]
    __shared__ unsigned short sV[128 * 72];   // [dv][key]   stride 144B
    __shared__ unsigned short sP[64 * 72];    // [qrow][key]
    __shared__ float sLpart[2][64];
    __shared__ float sLinv[64];
    __shared__ float sMsk[64];

    // XCD-aware swizzle: XCD x handles batches {2x, 2x+1} -> K/V L2-resident
    int bi = blockIdx.x;
    int slot = bi >> 3;
    int b = (bi & 7) * 2 + (slot >> 5);
    int qt = slot & 31;

    int tid = threadIdx.x;
    int wave = tid >> 6, lane = tid & 63, lo = lane & 15, hi = lane >> 4;

    // stage Q tile (64 x 128 bf16) once
    const unsigned short* Qbase = Qb + (size_t)(b * SS + qt * 64) * DD;
#pragma unroll
    for (int rnd = 0; rnd < 4; ++rnd) {
        int sl = rnd * 256 + tid;
        int row = sl >> 4, coff = (sl & 15) * 8;
        *(int4*)&sQ[row * 136 + coff] = *(const int4*)(Qbase + row * DD + coff);
    }
    if (tid < 64) { sLpart[0][tid] = 0.f; sLpart[1][tid] = 0.f; }

    const int r0 = (wave >> 1) * 32;  // S quadrant rows
    const int c0 = (wave & 1) * 32;   // S quadrant cols

    // ---------- phase 1: row sums l ----------
    for (int kt = 0; kt < 32; ++kt) {
        __syncthreads();
        const unsigned short* Kbase = Kb + (size_t)(b * SS + kt * 64) * DD;
#pragma unroll
        for (int rnd = 0; rnd < 4; ++rnd) {
            int sl = rnd * 256 + tid;
            int row = sl >> 4, coff = (sl & 15) * 8;
            *(int4*)&sK[row * 136 + coff] = *(const int4*)(Kbase + row * DD + coff);
        }
        if (tid < 64) sMsk[tid] = mask[b * SS + kt * 64 + tid] ? 1.f : 0.f;
        __syncthreads();

        f32x4 acc[2][2];
#pragma unroll
        for (int ii = 0; ii < 2; ++ii)
#pragma unroll
            for (int jj = 0; jj < 2; ++jj) acc[ii][jj] = (f32x4){0.f, 0.f, 0.f, 0.f};
#pragma unroll
        for (int ks = 0; ks < 4; ++ks) {
            bf16x8 af[2], bf[2];
#pragma unroll
            for (int ii = 0; ii < 2; ++ii)
                af[ii] = *(const bf16x8*)&sQ[(r0 + ii * 16 + lo) * 136 + ks * 32 + hi * 8];
#pragma unroll
            for (int jj = 0; jj < 2; ++jj)
                bf[jj] = *(const bf16x8*)&sK[(c0 + jj * 16 + lo) * 136 + ks * 32 + hi * 8];
#pragma unroll
            for (int ii = 0; ii < 2; ++ii)
#pragma unroll
                for (int jj = 0; jj < 2; ++jj)
                    acc[ii][jj] = __builtin_amdgcn_mfma_f32_16x16x32_bf16(af[ii], bf[jj], acc[ii][jj], 0, 0, 0);
        }
        float m0 = sMsk[c0 + lo], m1 = sMsk[c0 + 16 + lo];
#pragma unroll
        for (int ii = 0; ii < 2; ++ii) {
#pragma unroll
            for (int r = 0; r < 4; ++r) {
                float v = __expf(acc[ii][0][r] * SCALE) * m0 + __expf(acc[ii][1][r] * SCALE) * m1;
                v += __shfl_xor(v, 1);
                v += __shfl_xor(v, 2);
                v += __shfl_xor(v, 4);
                v += __shfl_xor(v, 8);
                if (lo == 0) sLpart[wave & 1][r0 + ii * 16 + hi * 4 + r] += v;
            }
        }
    }
    __syncthreads();
    if (tid < 64) sLinv[tid] = 1.f / (sLpart[0][tid] + sLpart[1][tid]);

    // ---------- phase 2: recompute S, write attn, accumulate O = P V ----------
    f32x4 oacc[4][2];
#pragma unroll
    for (int mi = 0; mi < 4; ++mi)
#pragma unroll
        for (int tj = 0; tj < 2; ++tj) oacc[mi][tj] = (f32x4){0.f, 0.f, 0.f, 0.f};
    const int dv0 = wave * 32;  // PV: wave owns dv columns [dv0, dv0+32)

    for (int kt = 0; kt < 32; ++kt) {
        __syncthreads();
        const unsigned short* Kbase = Kb + (size_t)(b * SS + kt * 64) * DD;
#pragma unroll
        for (int rnd = 0; rnd < 4; ++rnd) {
            int sl = rnd * 256 + tid;
            int row = sl >> 4, coff = (sl & 15) * 8;
            *(int4*)&sK[row * 136 + coff] = *(const int4*)(Kbase + row * DD + coff);
        }
#pragma unroll
        for (int rnd = 0; rnd < 4; ++rnd) {
            int sl = rnd * 256 + tid;
            int row = sl >> 3, koff = (sl & 7) * 8;  // row = dv 0..127
            *(int4*)&sV[row * 72 + koff] =
                *(const int4*)(Vt + (size_t)(b * DD + row) * SS + kt * 64 + koff);
        }
        if (tid < 64) sMsk[tid] = mask[b * SS + kt * 64 + tid] ? 1.f : 0.f;
        __syncthreads();

        f32x4 acc[2][2];
#pragma unroll
        for (int ii = 0; ii < 2; ++ii)
#pragma unroll
            for (int jj = 0; jj < 2; ++jj) acc[ii][jj] = (f32x4){0.f, 0.f, 0.f, 0.f};
#pragma unroll
        for (int ks = 0; ks < 4; ++ks) {
            bf16x8 af[2], bf[2];
#pragma unroll
            for (int ii = 0; ii < 2; ++ii)
                af[ii] = *(const bf16x8*)&sQ[(r0 + ii * 16 + lo) * 136 + ks * 32 + hi * 8];
#pragma unroll
            for (int jj = 0; jj < 2; ++jj)
                bf[jj] = *(const bf16x8*)&sK[(c0 + jj * 16 + lo) * 136 + ks * 32 + hi * 8];
#pragma unroll
            for (int ii = 0; ii < 2; ++ii)
#pragma unroll
                for (int jj = 0; jj < 2; ++jj)
                    acc[ii][jj] = __builtin_amdgcn_mfma_f32_16x16x32_bf16(af[ii], bf[jj], acc[ii][jj], 0, 0, 0);
        }
        float m01[2] = {sMsk[c0 + lo], sMsk[c0 + 16 + lo]};
#pragma unroll
        for (int ii = 0; ii < 2; ++ii) {
#pragma unroll
            for (int jj = 0; jj < 2; ++jj) {
#pragma unroll
                for (int r = 0; r < 4; ++r) {
                    int row = r0 + ii * 16 + hi * 4 + r;
                    int col = c0 + jj * 16 + lo;
                    float p = __expf(acc[ii][jj][r] * SCALE) * m01[jj] * sLinv[row];
                    outA[(size_t)(b * SS + qt * 64 + row) * SS + kt * 64 + col] = p;
                    sP[row * 72 + col] = f2bf(p);
                }
            }
        }
        __syncthreads();

        // O += P (64 x 64) @ V (64 x 128), wave owns 32 dv columns
#pragma unroll
        for (int ks = 0; ks < 2; ++ks) {
            bf16x8 pa[4], vb[2];
#pragma unroll
            for (int mi = 0; mi < 4; ++mi)
                pa[mi] = *(const bf16x8*)&sP[(mi * 16 + lo) * 72 + ks * 32 + hi * 8];
#pragma unroll
            for (int tj = 0; tj < 2; ++tj)
                vb[tj] = *(const bf16x8*)&sV[(dv0 + tj * 16 + lo) * 72 + ks * 32 + hi * 8];
#pragma unroll
            for (int mi = 0; mi < 4; ++mi)
#pragma unroll
                for (int tj = 0; tj < 2; ++tj)
                    oacc[mi][tj] = __builtin_amdgcn_mfma_f32_16x16x32_bf16(pa[mi], vb[tj], oacc[mi][tj], 0, 0, 0);
        }
    }

    // write O
#pragma unroll
    for (int mi = 0; mi < 4; ++mi) {
#pragma unroll
        for (int tj = 0; tj < 2; ++tj) {
#pragma unroll
            for (int r = 0; r < 4; ++r) {
                int row = mi * 16 + hi * 4 + r;
                int dv = dv0 + tj * 16 + lo;
                outO[(size_t)(b * SS + qt * 64 + row) * DD + dv] = oacc[mi][tj][r];
            }
        }
    }
}

extern "C" void kernel_launch(void* const* d_in, const int* in_sizes, int n_in,
                              void* d_out, int out_size, void* d_ws, size_t ws_size,
                              hipStream_t stream) {
    const float* Q = (const float*)d_in[0];
    const float* K = (const float*)d_in[1];
    const float* V = (const float*)d_in[2];
    const int* mask = (const int*)d_in[3];

    float* outO = (float*)d_out;                          // [B,S,D]
    float* outA = outO + (size_t)BB * SS * DD;            // [B,S,S]

    unsigned short* Qb = (unsigned short*)d_ws;           // bf16 [B,S,D]  8 MiB
    unsigned short* Kb = Qb + (size_t)BB * SS * DD;       // bf16 [B,S,D]  8 MiB
    unsigned short* Vt = Kb + (size_t)BB * SS * DD;       // bf16 [B,D,S]  8 MiB

    int nconv = (BB * SS * DD) / (256 * 4);               // 4096 blocks
    cvt_bf16_kernel<<<nconv, 256, 0, stream>>>(Q, Qb);
    cvt_bf16_kernel<<<nconv, 256, 0, stream>>>(K, Kb);
    transpose_v_kernel<<<BB * (SS / 64), 256, 0, stream>>>(V, Vt);
    attn_kernel<<<BB * (SS / 64), 256, 0, stream>>>(Qb, Kb, Vt, mask, outO, outA);
}